// Round 12
// baseline (75897.687 us; speedup 1.0000x reference)
//
#include <hip/hip_runtime.h>
#include <math.h>

// ---------------------------------------------------------------------------
// 2-layer tanh RNN scan, B=128, T=1024, H=768.  Persistent kernel, 256 WGs.
// Round-12 = round-10's EXACT structure/dep-graph (best: 9.59 ms), templated
// LOCAL/AGENT per group.
// Coherence theory (consistent with r2/3/5/6/7/10 evidence): gfx950 L1 is
// WRITE-BACK for plain stores; `sc0` store = write-through to L2; plain/sc0
// loads may hit stale L1; atomics always bypass L1.  Therefore:
//   LOCAL (group co-resident on one XCD, runtime-verified):
//     data store : global_store_dword sc0        (lands in XCD L2)
//     flag arrive: global_atomic_swap            (L2-local, no return)
//     flag poll  : global_atomic_add 0 sc0       (L2 read, L1-bypass)
//     acquire    : buffer_inv sc0                (L1-only invalidate; L2
//                  intact -> bulk reloads are L2 HITS, not HBM refetch)
//   AGENT fallback (any placement): r10's proven sc0 sc1 recipe verbatim.
// Roles per group (32 WGs, 16 batch rows): 8x L1 (96 cols W_hh1),
// 24x L2 (32 cols W_ih2+W_hh2).  4-slot h1, 2-slot h2, 4-slot P; off-path
// out-reduce gates the h1 slots (fP1-free).  Numerics: bf16 (hi,lo) pairs,
// 3-product MFMA, fp32 accumulate (proven, absmax 2.4e-4).
// ---------------------------------------------------------------------------

typedef short s16x8 __attribute__((ext_vector_type(8)));
typedef float fx4   __attribute__((ext_vector_type(4)));

#define NWG    256
#define T_LEN  1024
#define H      768
#define GROUPS 8
#define GROWS  16

// ws layout (bytes)
#define MAP_OFF    0          // u32[256]
#define KBR_OFF    1024       // u32[256]
#define GRP_BASE   8192
#define G_FL1 0               // u32[8]
#define G_FH2 128             // u32[24]
#define G_PB  512             // float[4][16][2][24] = 12288B
#define G_H1  16384           // 4 slots x {hi,lo} x 24576B
#define G_H2  212992          // 2 slots x {hi,lo} x 24576B
#define GRP_STRIDE 315392
#define HB_SZ 24576
#define WS_TOTAL (GRP_BASE + GROUPS * GRP_STRIDE)

__device__ __forceinline__ unsigned short f2bf(float x) {
    unsigned u = __float_as_uint(x);
    unsigned r = (u + 0x7FFFu + ((u >> 16) & 1u)) >> 16;   // RNE
    return (unsigned short)r;
}
__device__ __forceinline__ float bf2f(unsigned short b) {
    return __uint_as_float(((unsigned)b) << 16);
}
__device__ __forceinline__ fx4 mfma16(s16x8 a, s16x8 b, fx4 c) {
    return __builtin_amdgcn_mfma_f32_16x16x32_bf16(a, b, c, 0, 0, 0);
}

// ---- AGENT primitives (r10-proven) -----------------------------------------
__device__ __forceinline__ void st_ag(unsigned* p, unsigned v) {
    __hip_atomic_store(p, v, __ATOMIC_RELAXED, __HIP_MEMORY_SCOPE_AGENT);
}
__device__ __forceinline__ unsigned ld_ag(const unsigned* p) {
    return __hip_atomic_load(p, __ATOMIC_RELAXED, __HIP_MEMORY_SCOPE_AGENT);
}
__device__ __forceinline__ void acq_ag() {
    __builtin_amdgcn_fence(__ATOMIC_ACQUIRE, "agent");
}
// ---- LOCAL primitives (XCD-L2 scope) ---------------------------------------
__device__ __forceinline__ void st32_sc0(unsigned* p, unsigned v) {
    asm volatile("global_store_dword %0, %1, off sc0" :: "v"(p), "v"(v) : "memory");
}
__device__ __forceinline__ void stflag_l2(unsigned* p, unsigned v) {
    asm volatile("global_atomic_swap %0, %1, off" :: "v"(p), "v"(v) : "memory");
}
__device__ __forceinline__ unsigned rdflag_l2(unsigned* p) {
    unsigned v, z = 0;
    asm volatile("global_atomic_add %0, %1, %2, off sc0\n\ts_waitcnt vmcnt(0)"
                 : "=v"(v) : "v"(p), "v"(z) : "memory");
    return v;
}
__device__ __forceinline__ void inv_l1() {
    asm volatile("buffer_inv sc0" ::: "memory");
}

template<bool LOCAL> __device__ __forceinline__ void stf(unsigned* p, unsigned v) {
    if constexpr (LOCAL) stflag_l2(p, v); else st_ag(p, v);
}
template<bool LOCAL> __device__ __forceinline__ unsigned rdf(unsigned* p) {
    if constexpr (LOCAL) return rdflag_l2(p); else return ld_ag(p);
}
template<bool LOCAL> __device__ __forceinline__ void std32(unsigned* p, unsigned v) {
    if constexpr (LOCAL) st32_sc0(p, v); else st_ag(p, v);
}
template<bool LOCAL> __device__ __forceinline__ void acq() {
    if constexpr (LOCAL) inv_l1(); else acq_ag();
}

__device__ __forceinline__ void load_wfrag(const float* __restrict__ W,
                                           int col, int kk, s16x8& hi, s16x8& lo) {
    const float* p = W + (long)col * H + kk;
#pragma unroll
    for (int j = 0; j < 8; j++) {
        float w = p[j];
        unsigned short h = f2bf(w);
        float r = w - bf2f(h);
        hi[j] = (short)h;
        lo[j] = (short)f2bf(r);
    }
}

__device__ __forceinline__ void ld6(const unsigned short* p, s16x8 (&d)[6]) {
#pragma unroll
    for (int ks = 0; ks < 6; ks++)
        d[ks] = *reinterpret_cast<const s16x8*>(p + ks * 32);
}

__device__ __forceinline__ unsigned wave_min(unsigned v) {
#pragma unroll
    for (int o = 32; o; o >>= 1) {
        unsigned u = (unsigned)__shfl_xor((int)v, o);
        v = v < u ? v : u;
    }
    return v;
}

// r10-proven wait: wave 0 polls, optional tid0 acquire, syncthreads.
template<bool LOCAL>
__device__ __forceinline__ void waitn(unsigned* f, int n, unsigned T,
                                      int tid, bool acquire) {
    if (tid < 64) {
        int l = tid < n ? tid : n - 1;
        long spin = 0;
        for (;;) {
            if (wave_min(rdf<LOCAL>(f + l)) >= T) break;
            __builtin_amdgcn_s_sleep(1);
            if (++spin > (1L << 20)) break;   // failsafe
        }
    }
    if (acquire && tid == 0) acq<LOCAL>();
    __syncthreads();
}

#define DRAIN() do { asm volatile("s_waitcnt vmcnt(0)" ::: "memory"); __syncthreads(); } while (0)

// ---------------------------------------------------------------------------
template<bool LOCAL>
__device__ __forceinline__ void run_group(
    int group, int lrank, int tid, int lane, int w, int l15, int lk8,
    const float* __restrict__ x,
    const float* __restrict__ Wih1, const float* __restrict__ Whh1,
    const float* __restrict__ bih1, const float* __restrict__ bhh1,
    const float* __restrict__ Wih2, const float* __restrict__ Whh2,
    const float* __restrict__ bih2, const float* __restrict__ bhh2,
    const float* __restrict__ Wlin, const float* __restrict__ blin,
    float* __restrict__ out, unsigned char* __restrict__ gb,
    float (*red)[16][97])
{
    unsigned* fL1 = (unsigned*)(gb + G_FL1);
    unsigned* fH2 = (unsigned*)(gb + G_FH2);
    float*    Pb  = (float*)(gb + G_PB);       // [4][16][2][24]
    const int kb0 = w * 192;

    if (lrank < 8) {
        // ========================= L1 role ==================================
        const int c = lrank;
        const int col0 = c * 96;

        s16x8 whi[6][6], wlo[6][6];
#pragma unroll
        for (int ks = 0; ks < 6; ks++)
#pragma unroll
            for (int nt = 0; nt < 6; nt++)
                load_wfrag(Whh1, col0 + nt * 16 + l15, kb0 + ks * 32 + lk8,
                           whi[ks][nt], wlo[ks][nt]);

        const int er = tid >> 4;                // row 0..15
        const int ec0 = (tid & 15) * 6;         // 6 consecutive cols
        const int b = group * GROWS + er;
        float bs[6], wi0[6], wi1[6];
#pragma unroll
        for (int j = 0; j < 6; j++) {
            int cg = col0 + ec0 + j;
            bs[j] = bih1[cg] + bhh1[cg];
            wi0[j] = Wih1[cg * 2 + 0];
            wi1[j] = Wih1[cg * 2 + 1];
        }
        const int ov = tid >> 5;                // 0..3 (tid<128)
        const int oj = tid & 31;
        const int orow = 2 * c + (ov >> 1);
        const int ooo = ov & 1;
        const float blv = blin[ooo];

        for (int t = 0; t < T_LEN; t++) {
            const int rs = (t + 3) & 3;         // h1(t-1) slot
            const int wsl = t & 3;              // h1(t) slot
            float x0 = x[b * 2048 + t];
            float x1 = x[b * 2048 + 1024 + t];

            // Top-of-iter off-path: fH2 gate (h1-slot guard) + out(t-3).
            if (t >= 3) {
                waitn<LOCAL>(fH2, 24, (unsigned)(t - 2), tid, false);
                if (tid < 128) {
                    float p = 0.f;
                    if (oj < 24)
                        p = __uint_as_float(rdf<LOCAL>((unsigned*)
                            (Pb + ((((t - 3) & 3) * 16 + orow) * 2 + ooo) * 24 + oj)));
#pragma unroll
                    for (int o = 16; o; o >>= 1) p += __shfl_down(p, o, 32);
                    if (oj == 0) out[(group * GROWS + orow) * 2048 + ooo * 1024 + (t - 3)] = p + blv;
                }
            }

            if (t) waitn<LOCAL>(fL1, 8, (unsigned)t, tid, true);   // h1(t-1) ready

            const unsigned short* Hh = (const unsigned short*)(gb + G_H1 + rs * 2 * HB_SZ);
            const unsigned short* Hl = (const unsigned short*)(gb + G_H1 + rs * 2 * HB_SZ + HB_SZ);
            s16x8 ah[6], al[6];
            ld6(Hh + l15 * H + kb0 + lk8, ah);
            ld6(Hl + l15 * H + kb0 + lk8, al);

            fx4 acc[6];
#pragma unroll
            for (int nt = 0; nt < 6; nt++) acc[nt] = fx4{0.f, 0.f, 0.f, 0.f};
#pragma unroll
            for (int ks = 0; ks < 6; ks++)
#pragma unroll
                for (int nt = 0; nt < 6; nt++) {
                    acc[nt] = mfma16(ah[ks], whi[ks][nt], acc[nt]);
                    acc[nt] = mfma16(ah[ks], wlo[ks][nt], acc[nt]);
                    acc[nt] = mfma16(al[ks], whi[ks][nt], acc[nt]);
                }

#pragma unroll
            for (int nt = 0; nt < 6; nt++)
#pragma unroll
                for (int i = 0; i < 4; i++)
                    red[w][(lane >> 4) * 4 + i][nt * 16 + l15] = acc[nt][i];
            __syncthreads();

            unsigned hw[3], lw[3];
#pragma unroll
            for (int jj = 0; jj < 3; jj++) {
                unsigned hp = 0, lp = 0;
#pragma unroll
                for (int k = 0; k < 2; k++) {
                    int j = jj * 2 + k;
                    int cc = ec0 + j;
                    float v = red[0][er][cc] + red[1][er][cc] + red[2][er][cc] + red[3][er][cc];
                    v += x0 * wi0[j] + x1 * wi1[j] + bs[j];
                    v = tanhf(v);
                    unsigned short hb = f2bf(v);
                    unsigned short lb = f2bf(v - bf2f(hb));
                    hp |= ((unsigned)hb) << (16 * k);
                    lp |= ((unsigned)lb) << (16 * k);
                }
                hw[jj] = hp; lw[jj] = lp;
            }

            unsigned* Dh = (unsigned*)(gb + G_H1 + wsl * 2 * HB_SZ) + ((long)er * H + col0 + ec0) / 2;
            unsigned* Dl = (unsigned*)(gb + G_H1 + wsl * 2 * HB_SZ + HB_SZ) + ((long)er * H + col0 + ec0) / 2;
            std32<LOCAL>(Dh + 0, hw[0]); std32<LOCAL>(Dh + 1, hw[1]); std32<LOCAL>(Dh + 2, hw[2]);
            std32<LOCAL>(Dl + 0, lw[0]); std32<LOCAL>(Dl + 1, lw[1]); std32<LOCAL>(Dl + 2, lw[2]);

            DRAIN();
            if (tid == 0) stf<LOCAL>(fL1 + c, (unsigned)(t + 1));
        }

        // tail: P(T-3..T-1)
        waitn<LOCAL>(fH2, 24, (unsigned)T_LEN, tid, false);
        if (tid < 128) {
#pragma unroll
            for (int par = 0; par < 3; par++) {
                int tt = T_LEN - 3 + par;
                float p = 0.f;
                if (oj < 24)
                    p = __uint_as_float(rdf<LOCAL>((unsigned*)
                        (Pb + (((tt & 3) * 16 + orow) * 2 + ooo) * 24 + oj)));
#pragma unroll
                for (int o = 16; o; o >>= 1) p += __shfl_down(p, o, 32);
                if (oj == 0) out[(group * GROWS + orow) * 2048 + ooo * 1024 + tt] = p + blv;
            }
        }
    } else {
        // ========================= L2 role ==================================
        const int q = lrank - 8;         // 0..23
        const int col0 = q * 32;

        s16x8 ghi[2][6], glo[2][6], ihi[2][6], ilo[2][6];
#pragma unroll
        for (int nt = 0; nt < 2; nt++)
#pragma unroll
            for (int ks = 0; ks < 6; ks++) {
                load_wfrag(Whh2, col0 + nt * 16 + l15, kb0 + ks * 32 + lk8, ghi[nt][ks], glo[nt][ks]);
                load_wfrag(Wih2, col0 + nt * 16 + l15, kb0 + ks * 32 + lk8, ihi[nt][ks], ilo[nt][ks]);
            }

        const int er = tid >> 4;             // 0..15
        const int ec0 = (tid & 15) * 2;      // 0..30
        const float bsA = bih2[col0 + ec0] + bhh2[col0 + ec0];
        const float bsB = bih2[col0 + ec0 + 1] + bhh2[col0 + ec0 + 1];

        const int ro = tid >> 1, oo = tid & 1;   // tid<32
        float wl[32];
        if (tid < 32) {
#pragma unroll
            for (int cc = 0; cc < 32; cc++) wl[cc] = Wlin[oo * H + col0 + cc];
        }

        for (int t = 0; t < T_LEN; t++) {
            const int rb = (t + 1) & 1;     // h2(t-1) slot
            const int wb = t & 1;           // h2(t) slot
            const int hs = t & 3;           // h1(t) slot

            if (t) waitn<LOCAL>(fH2, 24, (unsigned)t, tid, true);   // h2(t-1) ready

            // phase 1: h2(t-1) @ W_hh2^T (overlaps h1(t) production)
            const unsigned short* Gh = (const unsigned short*)(gb + G_H2 + rb * 2 * HB_SZ);
            const unsigned short* Gl = (const unsigned short*)(gb + G_H2 + rb * 2 * HB_SZ + HB_SZ);
            s16x8 ah[6], al[6];
            ld6(Gh + l15 * H + kb0 + lk8, ah);
            ld6(Gl + l15 * H + kb0 + lk8, al);

            fx4 a2[2];
            a2[0] = fx4{0.f, 0.f, 0.f, 0.f};
            a2[1] = fx4{0.f, 0.f, 0.f, 0.f};
#pragma unroll
            for (int ks = 0; ks < 6; ks++)
#pragma unroll
                for (int nt = 0; nt < 2; nt++) {
                    a2[nt] = mfma16(ah[ks], ghi[nt][ks], a2[nt]);
                    a2[nt] = mfma16(ah[ks], glo[nt][ks], a2[nt]);
                    a2[nt] = mfma16(al[ks], ghi[nt][ks], a2[nt]);
                }

            waitn<LOCAL>(fL1, 8, (unsigned)(t + 1), tid, true);     // h1(t) ready

            // phase 3: += h1(t) @ W_ih2^T
            const unsigned short* Hh = (const unsigned short*)(gb + G_H1 + hs * 2 * HB_SZ);
            const unsigned short* Hl = (const unsigned short*)(gb + G_H1 + hs * 2 * HB_SZ + HB_SZ);
            ld6(Hh + l15 * H + kb0 + lk8, ah);
            ld6(Hl + l15 * H + kb0 + lk8, al);
#pragma unroll
            for (int ks = 0; ks < 6; ks++)
#pragma unroll
                for (int nt = 0; nt < 2; nt++) {
                    a2[nt] = mfma16(ah[ks], ihi[nt][ks], a2[nt]);
                    a2[nt] = mfma16(ah[ks], ilo[nt][ks], a2[nt]);
                    a2[nt] = mfma16(al[ks], ihi[nt][ks], a2[nt]);
                }

#pragma unroll
            for (int nt = 0; nt < 2; nt++)
#pragma unroll
                for (int i = 0; i < 4; i++)
                    red[w][(lane >> 4) * 4 + i][nt * 16 + l15] = a2[nt][i];
            __syncthreads();

            float v0 = red[0][er][ec0] + red[1][er][ec0] + red[2][er][ec0] + red[3][er][ec0] + bsA;
            float v1 = red[0][er][ec0 + 1] + red[1][er][ec0 + 1] + red[2][er][ec0 + 1] + red[3][er][ec0 + 1] + bsB;
            v0 = tanhf(v0); v1 = tanhf(v1);
            unsigned short hb0 = f2bf(v0), hb1 = f2bf(v1);
            unsigned hp = ((unsigned)hb0) | (((unsigned)hb1) << 16);
            unsigned lp = ((unsigned)f2bf(v0 - bf2f(hb0))) | (((unsigned)f2bf(v1 - bf2f(hb1))) << 16);
            unsigned* Dh = (unsigned*)(gb + G_H2 + wb * 2 * HB_SZ) + ((long)er * H + col0 + ec0) / 2;
            unsigned* Dl = (unsigned*)(gb + G_H2 + wb * 2 * HB_SZ + HB_SZ) + ((long)er * H + col0 + ec0) / 2;
            std32<LOCAL>(Dh, hp);
            std32<LOCAL>(Dl, lp);
            red[0][er][ec0] = v0;
            red[0][er][ec0 + 1] = v1;
            __syncthreads();

            if (tid < 32) {
                float s = 0.f;
#pragma unroll
                for (int cc = 0; cc < 32; cc++) s += red[0][ro][cc] * wl[cc];
                std32<LOCAL>((unsigned*)&Pb[(((t & 3) * 16 + ro) * 2 + oo) * 24 + q],
                             __float_as_uint(s));
            }

            DRAIN();
            if (tid == 0) stf<LOCAL>(fH2 + q, (unsigned)(t + 1));
        }
    }
}

// ---------------------------------------------------------------------------
__global__ __launch_bounds__(256, 1) void rnn_persist(
    const float* __restrict__ x,
    const float* __restrict__ Wih1, const float* __restrict__ Whh1,
    const float* __restrict__ bih1, const float* __restrict__ bhh1,
    const float* __restrict__ Wih2, const float* __restrict__ Whh2,
    const float* __restrict__ bih2, const float* __restrict__ bhh2,
    const float* __restrict__ Wlin, const float* __restrict__ blin,
    float* __restrict__ out, unsigned char* __restrict__ ws)
{
    const int wg = blockIdx.x;
    const int tid = threadIdx.x;
    const int lane = tid & 63;
    const int w = tid >> 6;
    const int l15 = lane & 15;
    const int lk8 = (lane >> 4) * 8;

    __shared__ float red[4][16][97];
    __shared__ int iscr[256];

    // ---- runtime XCD discovery (agent scope, r5/r6-proven) -----------------
    unsigned* map = (unsigned*)(ws + MAP_OFF);
    unsigned* kbr = (unsigned*)(ws + KBR_OFF);

    int key;
    asm volatile("s_getreg_b32 %0, hwreg(HW_REG_XCC_ID, 0, 4)" : "=s"(key));
    key &= 0xF;

    if (tid == 0) st_ag(map + wg, (unsigned)(key + 1));
    unsigned kj;
    {
        long spin = 0;
        for (;;) {
            kj = ld_ag(map + tid);
            if (kj) break;
            __builtin_amdgcn_s_sleep(2);
            if (++spin > (1L << 20)) break;
        }
    }
    int contrib = (((int)kj - 1) < key || (((int)kj - 1) == key && tid < wg)) ? 1 : 0;
    iscr[tid] = contrib;
    __syncthreads();
#pragma unroll
    for (int s = 128; s; s >>= 1) {
        if (tid < s) iscr[tid] += iscr[tid + s];
        __syncthreads();
    }
    const int rank = iscr[0];
    __syncthreads();
    const int group = rank >> 5, lrank = rank & 31;

    if (tid == 0) st_ag(kbr + rank, (unsigned)(key + 1));
    unsigned kv;
    {
        long spin = 0;
        for (;;) {
            kv = ld_ag(kbr + tid);
            if (kv) break;
            __builtin_amdgcn_s_sleep(2);
            if (++spin > (1L << 20)) break;
        }
    }
    int eq = ((int)kv - 1 == key) ? 1 : 0;
    int bad = ((tid >> 5) == group && !eq) ? 1 : 0;
    iscr[tid] = eq | (bad << 16);
    __syncthreads();
#pragma unroll
    for (int s = 128; s; s >>= 1) {
        if (tid < s) iscr[tid] += iscr[tid + s];
        __syncthreads();
    }
    const int r0 = iscr[0];
    __syncthreads();
    const bool local = ((r0 & 0xFFFF) == 32) && ((r0 >> 16) == 0);

    unsigned char* gb = ws + GRP_BASE + (size_t)group * GRP_STRIDE;

    if (local)
        run_group<true>(group, lrank, tid, lane, w, l15, lk8,
                        x, Wih1, Whh1, bih1, bhh1, Wih2, Whh2, bih2, bhh2,
                        Wlin, blin, out, gb, red);
    else
        run_group<false>(group, lrank, tid, lane, w, l15, lk8,
                         x, Wih1, Whh1, bih1, bhh1, Wih2, Whh2, bih2, bhh2,
                         Wlin, blin, out, gb, red);
}

extern "C" void kernel_launch(void* const* d_in, const int* in_sizes, int n_in,
                              void* d_out, int out_size, void* d_ws, size_t ws_size,
                              hipStream_t stream) {
    const float* x    = (const float*)d_in[0];
    const float* Wih1 = (const float*)d_in[1];
    const float* Whh1 = (const float*)d_in[2];
    const float* bih1 = (const float*)d_in[3];
    const float* bhh1 = (const float*)d_in[4];
    const float* Wih2 = (const float*)d_in[5];
    const float* Whh2 = (const float*)d_in[6];
    const float* bih2 = (const float*)d_in[7];
    const float* bhh2 = (const float*)d_in[8];
    const float* Wlin = (const float*)d_in[9];
    const float* blin = (const float*)d_in[10];

    // Zero discovery tables, flags, h-state (initial h = 0).
    hipMemsetAsync(d_ws, 0, WS_TOTAL, stream);

    rnn_persist<<<NWG, 256, 0, stream>>>(x, Wih1, Whh1, bih1, bhh1,
                                         Wih2, Whh2, bih2, bhh2,
                                         Wlin, blin, (float*)d_out,
                                         (unsigned char*)d_ws);
}

// Round 14
// 6886.365 us; speedup vs baseline: 11.0214x; 11.0214x over previous
//
#include <hip/hip_runtime.h>
#include <math.h>

// ---------------------------------------------------------------------------
// 2-layer tanh RNN scan, B=128, T=1024, H=768.  Persistent kernel, 256 WGs.
// Round-14 = round-12 (LOCAL/XCD-L2 coherence CONFIRMED: absmax 2.4e-4,
// FETCH_SIZE 3.2GB->88MB) with the atomic-poll STORM removed:
//   r12 bug: all 56 inactive lanes polled f[n-1] -> ~1792 same-address RMWs
//   per round per group serializing at the TCC (-> 75 ms).  r13's sc0-load
//   polls proved UNRELIABLE (stale even with buffer_inv).  r14:
//   * polls: ONLY lanes tid<n issue global_atomic_add(p,0) sc0 (distinct
//     addresses; 32 RMWs/addr/round).  Observed min broadcast via LDS and
//     CACHED per wait-site; cache-satisfied waits skip polling entirely.
//   * every LOCAL wait (cached or not) still ends with tid0 buffer_inv sc0
//     + syncthreads (h-slot addresses alias every 2-4 steps; inv is local).
//   * data: sc0 stores -> XCD L2; plain loads after inv = L2 hits (proven).
//   * P-partial reads: distinct-address atomics (proven fresh, parallel).
//   * flag arrive: global_atomic_swap at local L2 (proven visible).
// AGENT fallback (non-co-resident groups): r10 verbatim (9.59 ms floor).
// Structure/dep-graph/numerics: r10/r12 verbatim.
// ---------------------------------------------------------------------------

typedef short s16x8 __attribute__((ext_vector_type(8)));
typedef float fx4   __attribute__((ext_vector_type(4)));

#define NWG    256
#define T_LEN  1024
#define H      768
#define GROUPS 8
#define GROWS  16

// ws layout (bytes)
#define MAP_OFF    0          // u32[256]
#define KBR_OFF    1024       // u32[256]
#define GRP_BASE   8192
#define G_FL1 0               // u32[8]
#define G_FH2 128             // u32[24]
#define G_PB  512             // float[4][16][2][24] = 12288B
#define G_H1  16384           // 4 slots x {hi,lo} x 24576B
#define G_H2  212992          // 2 slots x {hi,lo} x 24576B
#define GRP_STRIDE 315392
#define HB_SZ 24576
#define WS_TOTAL (GRP_BASE + GROUPS * GRP_STRIDE)

__device__ __forceinline__ unsigned short f2bf(float x) {
    unsigned u = __float_as_uint(x);
    unsigned r = (u + 0x7FFFu + ((u >> 16) & 1u)) >> 16;   // RNE
    return (unsigned short)r;
}
__device__ __forceinline__ float bf2f(unsigned short b) {
    return __uint_as_float(((unsigned)b) << 16);
}
__device__ __forceinline__ fx4 mfma16(s16x8 a, s16x8 b, fx4 c) {
    return __builtin_amdgcn_mfma_f32_16x16x32_bf16(a, b, c, 0, 0, 0);
}

// ---- AGENT primitives (r10-proven) -----------------------------------------
__device__ __forceinline__ void st_ag(unsigned* p, unsigned v) {
    __hip_atomic_store(p, v, __ATOMIC_RELAXED, __HIP_MEMORY_SCOPE_AGENT);
}
__device__ __forceinline__ unsigned ld_ag(const unsigned* p) {
    return __hip_atomic_load(p, __ATOMIC_RELAXED, __HIP_MEMORY_SCOPE_AGENT);
}
__device__ __forceinline__ void acq_ag() {
    __builtin_amdgcn_fence(__ATOMIC_ACQUIRE, "agent");
}
// ---- LOCAL primitives (XCD-L2 scope; ALL r12-proven) -----------------------
__device__ __forceinline__ void st32_sc0(unsigned* p, unsigned v) {
    asm volatile("global_store_dword %0, %1, off sc0" :: "v"(p), "v"(v) : "memory");
}
__device__ __forceinline__ void stflag_l2(unsigned* p, unsigned v) {
    asm volatile("global_atomic_swap %0, %1, off" :: "v"(p), "v"(v) : "memory");
}
__device__ __forceinline__ unsigned rdflag_l2(unsigned* p) {
    unsigned v, z = 0;
    asm volatile("global_atomic_add %0, %1, %2, off sc0\n\ts_waitcnt vmcnt(0)"
                 : "=v"(v) : "v"(p), "v"(z) : "memory");
    return v;
}
__device__ __forceinline__ void inv_l1() {     // CU L1 invalidate (L2 intact)
    asm volatile("buffer_inv sc0" ::: "memory");
}

template<bool LOCAL> __device__ __forceinline__ void stf(unsigned* p, unsigned v) {
    if constexpr (LOCAL) stflag_l2(p, v); else st_ag(p, v);
}
template<bool LOCAL> __device__ __forceinline__ unsigned rdp(unsigned* p) {
    if constexpr (LOCAL) return rdflag_l2(p); else return ld_ag(p);
}
template<bool LOCAL> __device__ __forceinline__ void std32(unsigned* p, unsigned v) {
    if constexpr (LOCAL) st32_sc0(p, v); else st_ag(p, v);
}

__device__ __forceinline__ void load_wfrag(const float* __restrict__ W,
                                           int col, int kk, s16x8& hi, s16x8& lo) {
    const float* p = W + (long)col * H + kk;
#pragma unroll
    for (int j = 0; j < 8; j++) {
        float w = p[j];
        unsigned short h = f2bf(w);
        float r = w - bf2f(h);
        hi[j] = (short)h;
        lo[j] = (short)f2bf(r);
    }
}

__device__ __forceinline__ void ld6(const unsigned short* p, s16x8 (&d)[6]) {
#pragma unroll
    for (int ks = 0; ks < 6; ks++)
        d[ks] = *reinterpret_cast<const s16x8*>(p + ks * 32);
}

__device__ __forceinline__ unsigned wave_min(unsigned v) {
#pragma unroll
    for (int o = 32; o; o >>= 1) {
        unsigned u = (unsigned)__shfl_xor((int)v, o);
        v = v < u ? v : u;
    }
    return v;
}

// LOCAL wait: cached-skip of the POLL; masked distinct-address atomic polls;
// unconditional tid0 buffer_inv (acquire) + syncthreads.  Returns observed
// min (>= T) for caching, broadcast via LDS slot `sh`.
__device__ __forceinline__ unsigned wait_local(unsigned* f, int n, unsigned T,
                                               int tid, unsigned cached,
                                               volatile unsigned* sh) {
    if (cached < T) {
        if (tid < 64) {
            unsigned m = 0;
            long spin = 0;
            for (;;) {
                unsigned v = (tid < n) ? rdflag_l2(f + tid) : 0xFFFFFFFFu;
                m = wave_min(v);
                if (m >= T) break;
                __builtin_amdgcn_s_sleep(2);
                if (++spin > (1L << 20)) break;   // failsafe
            }
            if (tid == 0) *sh = m;
        }
    }
    if (tid == 0) inv_l1();
    __syncthreads();
    return (cached < T) ? *sh : cached;
}

// AGENT wait: r10 verbatim.
__device__ __forceinline__ void wait_agent(unsigned* f, int n, unsigned T,
                                           int tid, bool acquire) {
    if (tid < 64) {
        int l = tid < n ? tid : n - 1;
        long spin = 0;
        for (;;) {
            if (wave_min(ld_ag(f + l)) >= T) break;
            __builtin_amdgcn_s_sleep(1);
            if (++spin > (1L << 20)) break;
        }
    }
    if (acquire && tid == 0) acq_ag();
    __syncthreads();
}

#define DRAIN() do { asm volatile("s_waitcnt vmcnt(0)" ::: "memory"); __syncthreads(); } while (0)

// ---------------------------------------------------------------------------
template<bool LOCAL>
__device__ __forceinline__ void run_group(
    int group, int lrank, int tid, int lane, int w, int l15, int lk8,
    const float* __restrict__ x,
    const float* __restrict__ Wih1, const float* __restrict__ Whh1,
    const float* __restrict__ bih1, const float* __restrict__ bhh1,
    const float* __restrict__ Wih2, const float* __restrict__ Whh2,
    const float* __restrict__ bih2, const float* __restrict__ bhh2,
    const float* __restrict__ Wlin, const float* __restrict__ blin,
    float* __restrict__ out, unsigned char* __restrict__ gb,
    float (*red)[16][97], volatile unsigned* shm)
{
    unsigned* fL1 = (unsigned*)(gb + G_FL1);
    unsigned* fH2 = (unsigned*)(gb + G_FH2);
    float*    Pb  = (float*)(gb + G_PB);       // [4][16][2][24]
    const int kb0 = w * 192;

    if (lrank < 8) {
        // ========================= L1 role ==================================
        const int c = lrank;
        const int col0 = c * 96;

        s16x8 whi[6][6], wlo[6][6];
#pragma unroll
        for (int ks = 0; ks < 6; ks++)
#pragma unroll
            for (int nt = 0; nt < 6; nt++)
                load_wfrag(Whh1, col0 + nt * 16 + l15, kb0 + ks * 32 + lk8,
                           whi[ks][nt], wlo[ks][nt]);

        const int er = tid >> 4;                // row 0..15
        const int ec0 = (tid & 15) * 6;         // 6 consecutive cols
        const int b = group * GROWS + er;
        float bs[6], wi0[6], wi1[6];
#pragma unroll
        for (int j = 0; j < 6; j++) {
            int cg = col0 + ec0 + j;
            bs[j] = bih1[cg] + bhh1[cg];
            wi0[j] = Wih1[cg * 2 + 0];
            wi1[j] = Wih1[cg * 2 + 1];
        }
        const int ov = tid >> 5;                // 0..3 (tid<128)
        const int oj = tid & 31;
        const int orow = 2 * c + (ov >> 1);
        const int ooo = ov & 1;
        const float blv = blin[ooo];

        unsigned fh2c = 0, fl1c = 0;

        for (int t = 0; t < T_LEN; t++) {
            const int rs = (t + 3) & 3;         // h1(t-1) slot
            const int wsl = t & 3;              // h1(t) slot
            float x0 = x[b * 2048 + t];
            float x1 = x[b * 2048 + 1024 + t];

            // Top-of-iter off-path: fH2 gate (h1-slot guard) + out(t-3).
            if (t >= 3) {
                if constexpr (LOCAL)
                    fh2c = wait_local(fH2, 24, (unsigned)(t - 2), tid, fh2c, &shm[0]);
                else
                    wait_agent(fH2, 24, (unsigned)(t - 2), tid, false);
                if (tid < 128) {
                    float p = 0.f;
                    if (oj < 24)
                        p = __uint_as_float(rdp<LOCAL>((unsigned*)
                            (Pb + ((((t - 3) & 3) * 16 + orow) * 2 + ooo) * 24 + oj)));
#pragma unroll
                    for (int o = 16; o; o >>= 1) p += __shfl_down(p, o, 32);
                    if (oj == 0) out[(group * GROWS + orow) * 2048 + ooo * 1024 + (t - 3)] = p + blv;
                }
            }

            if (t) {
                if constexpr (LOCAL)
                    fl1c = wait_local(fL1, 8, (unsigned)t, tid, fl1c, &shm[1]);
                else
                    wait_agent(fL1, 8, (unsigned)t, tid, true);
            }

            const unsigned short* Hh = (const unsigned short*)(gb + G_H1 + rs * 2 * HB_SZ);
            const unsigned short* Hl = (const unsigned short*)(gb + G_H1 + rs * 2 * HB_SZ + HB_SZ);
            s16x8 ah[6], al[6];
            ld6(Hh + l15 * H + kb0 + lk8, ah);
            ld6(Hl + l15 * H + kb0 + lk8, al);

            fx4 acc[6];
#pragma unroll
            for (int nt = 0; nt < 6; nt++) acc[nt] = fx4{0.f, 0.f, 0.f, 0.f};
#pragma unroll
            for (int ks = 0; ks < 6; ks++)
#pragma unroll
                for (int nt = 0; nt < 6; nt++) {
                    acc[nt] = mfma16(ah[ks], whi[ks][nt], acc[nt]);
                    acc[nt] = mfma16(ah[ks], wlo[ks][nt], acc[nt]);
                    acc[nt] = mfma16(al[ks], whi[ks][nt], acc[nt]);
                }

#pragma unroll
            for (int nt = 0; nt < 6; nt++)
#pragma unroll
                for (int i = 0; i < 4; i++)
                    red[w][(lane >> 4) * 4 + i][nt * 16 + l15] = acc[nt][i];
            __syncthreads();

            unsigned hw[3], lw[3];
#pragma unroll
            for (int jj = 0; jj < 3; jj++) {
                unsigned hp = 0, lp = 0;
#pragma unroll
                for (int k = 0; k < 2; k++) {
                    int j = jj * 2 + k;
                    int cc = ec0 + j;
                    float v = red[0][er][cc] + red[1][er][cc] + red[2][er][cc] + red[3][er][cc];
                    v += x0 * wi0[j] + x1 * wi1[j] + bs[j];
                    v = tanhf(v);
                    unsigned short hb = f2bf(v);
                    unsigned short lb = f2bf(v - bf2f(hb));
                    hp |= ((unsigned)hb) << (16 * k);
                    lp |= ((unsigned)lb) << (16 * k);
                }
                hw[jj] = hp; lw[jj] = lp;
            }

            unsigned* Dh = (unsigned*)(gb + G_H1 + wsl * 2 * HB_SZ) + ((long)er * H + col0 + ec0) / 2;
            unsigned* Dl = (unsigned*)(gb + G_H1 + wsl * 2 * HB_SZ + HB_SZ) + ((long)er * H + col0 + ec0) / 2;
            std32<LOCAL>(Dh + 0, hw[0]); std32<LOCAL>(Dh + 1, hw[1]); std32<LOCAL>(Dh + 2, hw[2]);
            std32<LOCAL>(Dl + 0, lw[0]); std32<LOCAL>(Dl + 1, lw[1]); std32<LOCAL>(Dl + 2, lw[2]);

            DRAIN();
            if (tid == 0) stf<LOCAL>(fL1 + c, (unsigned)(t + 1));
        }

        // tail: P(T-3..T-1)
        if constexpr (LOCAL)
            fh2c = wait_local(fH2, 24, (unsigned)T_LEN, tid, fh2c, &shm[0]);
        else
            wait_agent(fH2, 24, (unsigned)T_LEN, tid, false);
        if (tid < 128) {
#pragma unroll
            for (int par = 0; par < 3; par++) {
                int tt = T_LEN - 3 + par;
                float p = 0.f;
                if (oj < 24)
                    p = __uint_as_float(rdp<LOCAL>((unsigned*)
                        (Pb + (((tt & 3) * 16 + orow) * 2 + ooo) * 24 + oj)));
#pragma unroll
                for (int o = 16; o; o >>= 1) p += __shfl_down(p, o, 32);
                if (oj == 0) out[(group * GROWS + orow) * 2048 + ooo * 1024 + tt] = p + blv;
            }
        }
    } else {
        // ========================= L2 role ==================================
        const int q = lrank - 8;         // 0..23
        const int col0 = q * 32;

        s16x8 ghi[2][6], glo[2][6], ihi[2][6], ilo[2][6];
#pragma unroll
        for (int nt = 0; nt < 2; nt++)
#pragma unroll
            for (int ks = 0; ks < 6; ks++) {
                load_wfrag(Whh2, col0 + nt * 16 + l15, kb0 + ks * 32 + lk8, ghi[nt][ks], glo[nt][ks]);
                load_wfrag(Wih2, col0 + nt * 16 + l15, kb0 + ks * 32 + lk8, ihi[nt][ks], ilo[nt][ks]);
            }

        const int er = tid >> 4;             // 0..15
        const int ec0 = (tid & 15) * 2;      // 0..30
        const float bsA = bih2[col0 + ec0] + bhh2[col0 + ec0];
        const float bsB = bih2[col0 + ec0 + 1] + bhh2[col0 + ec0 + 1];

        const int ro = tid >> 1, oo = tid & 1;   // tid<32
        float wl[32];
        if (tid < 32) {
#pragma unroll
            for (int cc = 0; cc < 32; cc++) wl[cc] = Wlin[oo * H + col0 + cc];
        }

        unsigned fh2c = 0, fl1c = 0;

        for (int t = 0; t < T_LEN; t++) {
            const int rb = (t + 1) & 1;     // h2(t-1) slot
            const int wb = t & 1;           // h2(t) slot
            const int hs = t & 3;           // h1(t) slot

            if (t) {
                if constexpr (LOCAL)
                    fh2c = wait_local(fH2, 24, (unsigned)t, tid, fh2c, &shm[2]);
                else
                    wait_agent(fH2, 24, (unsigned)t, tid, true);
            }

            // phase 1: h2(t-1) @ W_hh2^T (overlaps h1(t) production)
            const unsigned short* Gh = (const unsigned short*)(gb + G_H2 + rb * 2 * HB_SZ);
            const unsigned short* Gl = (const unsigned short*)(gb + G_H2 + rb * 2 * HB_SZ + HB_SZ);
            s16x8 ah[6], al[6];
            ld6(Gh + l15 * H + kb0 + lk8, ah);
            ld6(Gl + l15 * H + kb0 + lk8, al);

            fx4 a2[2];
            a2[0] = fx4{0.f, 0.f, 0.f, 0.f};
            a2[1] = fx4{0.f, 0.f, 0.f, 0.f};
#pragma unroll
            for (int ks = 0; ks < 6; ks++)
#pragma unroll
                for (int nt = 0; nt < 2; nt++) {
                    a2[nt] = mfma16(ah[ks], ghi[nt][ks], a2[nt]);
                    a2[nt] = mfma16(ah[ks], glo[nt][ks], a2[nt]);
                    a2[nt] = mfma16(al[ks], ghi[nt][ks], a2[nt]);
                }

            if constexpr (LOCAL)
                fl1c = wait_local(fL1, 8, (unsigned)(t + 1), tid, fl1c, &shm[3]);
            else
                wait_agent(fL1, 8, (unsigned)(t + 1), tid, true);

            // phase 3: += h1(t) @ W_ih2^T
            const unsigned short* Hh = (const unsigned short*)(gb + G_H1 + hs * 2 * HB_SZ);
            const unsigned short* Hl = (const unsigned short*)(gb + G_H1 + hs * 2 * HB_SZ + HB_SZ);
            ld6(Hh + l15 * H + kb0 + lk8, ah);
            ld6(Hl + l15 * H + kb0 + lk8, al);
#pragma unroll
            for (int ks = 0; ks < 6; ks++)
#pragma unroll
                for (int nt = 0; nt < 2; nt++) {
                    a2[nt] = mfma16(ah[ks], ihi[nt][ks], a2[nt]);
                    a2[nt] = mfma16(ah[ks], ilo[nt][ks], a2[nt]);
                    a2[nt] = mfma16(al[ks], ihi[nt][ks], a2[nt]);
                }

#pragma unroll
            for (int nt = 0; nt < 2; nt++)
#pragma unroll
                for (int i = 0; i < 4; i++)
                    red[w][(lane >> 4) * 4 + i][nt * 16 + l15] = a2[nt][i];
            __syncthreads();

            float v0 = red[0][er][ec0] + red[1][er][ec0] + red[2][er][ec0] + red[3][er][ec0] + bsA;
            float v1 = red[0][er][ec0 + 1] + red[1][er][ec0 + 1] + red[2][er][ec0 + 1] + red[3][er][ec0 + 1] + bsB;
            v0 = tanhf(v0); v1 = tanhf(v1);
            unsigned short hb0 = f2bf(v0), hb1 = f2bf(v1);
            unsigned hp = ((unsigned)hb0) | (((unsigned)hb1) << 16);
            unsigned lp = ((unsigned)f2bf(v0 - bf2f(hb0))) | (((unsigned)f2bf(v1 - bf2f(hb1))) << 16);
            unsigned* Dh = (unsigned*)(gb + G_H2 + wb * 2 * HB_SZ) + ((long)er * H + col0 + ec0) / 2;
            unsigned* Dl = (unsigned*)(gb + G_H2 + wb * 2 * HB_SZ + HB_SZ) + ((long)er * H + col0 + ec0) / 2;
            std32<LOCAL>(Dh, hp);
            std32<LOCAL>(Dl, lp);
            red[0][er][ec0] = v0;
            red[0][er][ec0 + 1] = v1;
            __syncthreads();

            if (tid < 32) {
                float s = 0.f;
#pragma unroll
                for (int cc = 0; cc < 32; cc++) s += red[0][ro][cc] * wl[cc];
                std32<LOCAL>((unsigned*)&Pb[(((t & 3) * 16 + ro) * 2 + oo) * 24 + q],
                             __float_as_uint(s));
            }

            DRAIN();
            if (tid == 0) stf<LOCAL>(fH2 + q, (unsigned)(t + 1));
        }
    }
}

// ---------------------------------------------------------------------------
__global__ __launch_bounds__(256, 1) void rnn_persist(
    const float* __restrict__ x,
    const float* __restrict__ Wih1, const float* __restrict__ Whh1,
    const float* __restrict__ bih1, const float* __restrict__ bhh1,
    const float* __restrict__ Wih2, const float* __restrict__ Whh2,
    const float* __restrict__ bih2, const float* __restrict__ bhh2,
    const float* __restrict__ Wlin, const float* __restrict__ blin,
    float* __restrict__ out, unsigned char* __restrict__ ws)
{
    const int wg = blockIdx.x;
    const int tid = threadIdx.x;
    const int lane = tid & 63;
    const int w = tid >> 6;
    const int l15 = lane & 15;
    const int lk8 = (lane >> 4) * 8;

    __shared__ float red[4][16][97];
    __shared__ int iscr[256];
    __shared__ unsigned shm[4];

    // ---- runtime XCD discovery (agent scope, r5/r6/r12-proven) -------------
    unsigned* map = (unsigned*)(ws + MAP_OFF);
    unsigned* kbr = (unsigned*)(ws + KBR_OFF);

    int key;
    asm volatile("s_getreg_b32 %0, hwreg(HW_REG_XCC_ID, 0, 4)" : "=s"(key));
    key &= 0xF;

    if (tid == 0) st_ag(map + wg, (unsigned)(key + 1));
    unsigned kj;
    {
        long spin = 0;
        for (;;) {
            kj = ld_ag(map + tid);
            if (kj) break;
            __builtin_amdgcn_s_sleep(2);
            if (++spin > (1L << 20)) break;
        }
    }
    int contrib = (((int)kj - 1) < key || (((int)kj - 1) == key && tid < wg)) ? 1 : 0;
    iscr[tid] = contrib;
    __syncthreads();
#pragma unroll
    for (int s = 128; s; s >>= 1) {
        if (tid < s) iscr[tid] += iscr[tid + s];
        __syncthreads();
    }
    const int rank = iscr[0];
    __syncthreads();
    const int group = rank >> 5, lrank = rank & 31;

    if (tid == 0) st_ag(kbr + rank, (unsigned)(key + 1));
    unsigned kv;
    {
        long spin = 0;
        for (;;) {
            kv = ld_ag(kbr + tid);
            if (kv) break;
            __builtin_amdgcn_s_sleep(2);
            if (++spin > (1L << 20)) break;
        }
    }
    int eq = ((int)kv - 1 == key) ? 1 : 0;
    int bad = ((tid >> 5) == group && !eq) ? 1 : 0;
    iscr[tid] = eq | (bad << 16);
    __syncthreads();
#pragma unroll
    for (int s = 128; s; s >>= 1) {
        if (tid < s) iscr[tid] += iscr[tid + s];
        __syncthreads();
    }
    const int r0 = iscr[0];
    __syncthreads();
    const bool local = ((r0 & 0xFFFF) == 32) && ((r0 >> 16) == 0);

    unsigned char* gb = ws + GRP_BASE + (size_t)group * GRP_STRIDE;

    if (local)
        run_group<true>(group, lrank, tid, lane, w, l15, lk8,
                        x, Wih1, Whh1, bih1, bhh1, Wih2, Whh2, bih2, bhh2,
                        Wlin, blin, out, gb, red, shm);
    else
        run_group<false>(group, lrank, tid, lane, w, l15, lk8,
                         x, Wih1, Whh1, bih1, bhh1, Wih2, Whh2, bih2, bhh2,
                         Wlin, blin, out, gb, red, shm);
}

extern "C" void kernel_launch(void* const* d_in, const int* in_sizes, int n_in,
                              void* d_out, int out_size, void* d_ws, size_t ws_size,
                              hipStream_t stream) {
    const float* x    = (const float*)d_in[0];
    const float* Wih1 = (const float*)d_in[1];
    const float* Whh1 = (const float*)d_in[2];
    const float* bih1 = (const float*)d_in[3];
    const float* bhh1 = (const float*)d_in[4];
    const float* Wih2 = (const float*)d_in[5];
    const float* Whh2 = (const float*)d_in[6];
    const float* bih2 = (const float*)d_in[7];
    const float* bhh2 = (const float*)d_in[8];
    const float* Wlin = (const float*)d_in[9];
    const float* blin = (const float*)d_in[10];

    // Zero discovery tables, flags, h-state (initial h = 0).
    hipMemsetAsync(d_ws, 0, WS_TOTAL, stream);

    rnn_persist<<<NWG, 256, 0, stream>>>(x, Wih1, Whh1, bih1, bhh1,
                                         Wih2, Whh2, bih2, bhh2,
                                         Wlin, blin, (float*)d_out,
                                         (unsigned char*)d_ws);
}

// Round 15
// 6462.479 us; speedup vs baseline: 11.7444x; 1.0656x over previous
//
#include <hip/hip_runtime.h>
#include <math.h>

// ---------------------------------------------------------------------------
// 2-layer tanh RNN scan, B=128, T=1024, H=768.  Persistent kernel, 256 WGs.
// Round-15 = round-14 (LOCAL XCD-L2 path proven: 6.89 ms, absmax 2.4e-4,
// FETCH 3.2GB->30MB) with the poll STORM replaced by publish/subscribe:
//   * arrive: swap own flag (r14) + vmcnt(0) + ONE raw poll round; if the
//     observed min >= own value (plausibly last arriver), publish min to 8
//     replicated epoch words (64B apart) via global_atomic_umax (monotone).
//     The globally-last committer's post-ack poll sees all flags >= T.
//   * wait: lane0 polls ONE epoch replica (lrank&7): ~4 same-address RMWs
//     per round (was 32-768).  Raw-poll failsafe every 8th round keeps
//     correctness independent of the publish path.
//   * L1's top anti-dep gate loses buffer_inv (atomic P-reads + write-only
//     guard need no L1 invalidation); cache-satisfied gates = syncthreads.
// Everything else r14-verbatim: sc0 data stores -> XCD L2; tid0 buffer_inv
// acquire + plain L2-hit loads; atomic P reads; agent fallback (r10) for
// non-co-resident groups; bf16 hi/lo 3-product MFMA numerics.
// ---------------------------------------------------------------------------

typedef short s16x8 __attribute__((ext_vector_type(8)));
typedef float fx4   __attribute__((ext_vector_type(4)));

#define NWG    256
#define T_LEN  1024
#define H      768
#define GROUPS 8
#define GROWS  16

// ws layout (bytes)
#define MAP_OFF    0          // u32[256]
#define KBR_OFF    1024       // u32[256]
#define GRP_BASE   8192
#define G_FL1 0               // u32[8]
#define G_FH2 128             // u32[24]
#define G_EL1 256             // 8 epoch replicas x 64B
#define G_EH2 768             // 8 epoch replicas x 64B
#define G_PB  2048            // float[4][16][2][24] = 12288B
#define G_H1  16384           // 4 slots x {hi,lo} x 24576B
#define G_H2  212992          // 2 slots x {hi,lo} x 24576B
#define GRP_STRIDE 315392
#define HB_SZ 24576
#define WS_TOTAL (GRP_BASE + GROUPS * GRP_STRIDE)

__device__ __forceinline__ unsigned short f2bf(float x) {
    unsigned u = __float_as_uint(x);
    unsigned r = (u + 0x7FFFu + ((u >> 16) & 1u)) >> 16;   // RNE
    return (unsigned short)r;
}
__device__ __forceinline__ float bf2f(unsigned short b) {
    return __uint_as_float(((unsigned)b) << 16);
}
__device__ __forceinline__ fx4 mfma16(s16x8 a, s16x8 b, fx4 c) {
    return __builtin_amdgcn_mfma_f32_16x16x32_bf16(a, b, c, 0, 0, 0);
}

// ---- AGENT primitives (r10-proven) -----------------------------------------
__device__ __forceinline__ void st_ag(unsigned* p, unsigned v) {
    __hip_atomic_store(p, v, __ATOMIC_RELAXED, __HIP_MEMORY_SCOPE_AGENT);
}
__device__ __forceinline__ unsigned ld_ag(const unsigned* p) {
    return __hip_atomic_load(p, __ATOMIC_RELAXED, __HIP_MEMORY_SCOPE_AGENT);
}
__device__ __forceinline__ void acq_ag() {
    __builtin_amdgcn_fence(__ATOMIC_ACQUIRE, "agent");
}
// ---- LOCAL primitives (XCD-L2 scope; r12/r14-proven) -----------------------
__device__ __forceinline__ void st32_sc0(unsigned* p, unsigned v) {
    asm volatile("global_store_dword %0, %1, off sc0" :: "v"(p), "v"(v) : "memory");
}
__device__ __forceinline__ void stflag_l2(unsigned* p, unsigned v) {
    asm volatile("global_atomic_swap %0, %1, off" :: "v"(p), "v"(v) : "memory");
}
__device__ __forceinline__ void umax_l2(unsigned* p, unsigned v) {
    asm volatile("global_atomic_umax %0, %1, off" :: "v"(p), "v"(v) : "memory");
}
__device__ __forceinline__ unsigned rdflag_l2(unsigned* p) {
    unsigned v, z = 0;
    asm volatile("global_atomic_add %0, %1, %2, off sc0\n\ts_waitcnt vmcnt(0)"
                 : "=v"(v) : "v"(p), "v"(z) : "memory");
    return v;
}
__device__ __forceinline__ void inv_l1() {     // CU L1 invalidate (L2 intact)
    asm volatile("buffer_inv sc0" ::: "memory");
}

template<bool LOCAL> __device__ __forceinline__ unsigned rdp(unsigned* p) {
    if constexpr (LOCAL) return rdflag_l2(p); else return ld_ag(p);
}
template<bool LOCAL> __device__ __forceinline__ void std32(unsigned* p, unsigned v) {
    if constexpr (LOCAL) st32_sc0(p, v); else st_ag(p, v);
}

__device__ __forceinline__ void load_wfrag(const float* __restrict__ W,
                                           int col, int kk, s16x8& hi, s16x8& lo) {
    const float* p = W + (long)col * H + kk;
#pragma unroll
    for (int j = 0; j < 8; j++) {
        float w = p[j];
        unsigned short h = f2bf(w);
        float r = w - bf2f(h);
        hi[j] = (short)h;
        lo[j] = (short)f2bf(r);
    }
}

__device__ __forceinline__ void ld6(const unsigned short* p, s16x8 (&d)[6]) {
#pragma unroll
    for (int ks = 0; ks < 6; ks++)
        d[ks] = *reinterpret_cast<const s16x8*>(p + ks * 32);
}

__device__ __forceinline__ unsigned wave_min(unsigned v) {
#pragma unroll
    for (int o = 32; o; o >>= 1) {
        unsigned u = (unsigned)__shfl_xor((int)v, o);
        v = v < u ? v : u;
    }
    return v;
}

// LOCAL arrive + epoch publish.  Own flag swap; vmcnt(0) (commit); one raw
// poll round (own value injected locally); publish min to 8 replicas iff
// min >= own value (the globally-last committer always qualifies).
__device__ __forceinline__ void arrive_pub(unsigned* own, unsigned ownval,
                                           unsigned* raw, int n, int ownidx,
                                           unsigned* reps, int tid) {
    if (tid == 0) stflag_l2(own, ownval);
    if (tid < 64) {
        asm volatile("s_waitcnt vmcnt(0)" ::: "memory");
        unsigned v = 0xFFFFFFFFu;
        if (tid < n) v = (tid == ownidx) ? ownval : rdflag_l2(raw + tid);
        unsigned m = wave_min(v);
        if (m >= ownval && tid < 8) umax_l2(reps + tid * 16, m);
    }
}

// LOCAL wait: epoch-replica poll (lane0, 1 RMW/round) + raw failsafe every
// 8th round; optional tid0 buffer_inv acquire; syncthreads; cached.
__device__ __forceinline__ unsigned wait_ep(unsigned* reps, unsigned* raw, int n,
                                            unsigned T, int tid, int lrank,
                                            unsigned cached, bool do_inv,
                                            volatile unsigned* sh) {
    if (cached < T) {
        if (tid < 64) {
            unsigned* myrep = reps + (lrank & 7) * 16;
            unsigned m = 0;
            long spin = 0;
            for (;;) {
                if ((spin & 7) == 7) {
                    unsigned v = (tid < n) ? rdflag_l2(raw + tid) : 0xFFFFFFFFu;
                    m = wave_min(v);
                } else {
                    if (tid == 0) m = rdflag_l2(myrep);
                    m = (unsigned)__shfl((int)m, 0);
                }
                if (m >= T) break;
                __builtin_amdgcn_s_sleep(1);
                if (++spin > (1L << 20)) break;   // failsafe
            }
            if (tid == 0) *sh = m;
        }
    }
    if (do_inv && tid == 0) inv_l1();
    __syncthreads();
    return (cached < T) ? *sh : cached;
}

// AGENT wait: r10 verbatim.
__device__ __forceinline__ void wait_agent(unsigned* f, int n, unsigned T,
                                           int tid, bool acquire) {
    if (tid < 64) {
        int l = tid < n ? tid : n - 1;
        long spin = 0;
        for (;;) {
            if (wave_min(ld_ag(f + l)) >= T) break;
            __builtin_amdgcn_s_sleep(1);
            if (++spin > (1L << 20)) break;
        }
    }
    if (acquire && tid == 0) acq_ag();
    __syncthreads();
}

#define DRAIN() do { asm volatile("s_waitcnt vmcnt(0)" ::: "memory"); __syncthreads(); } while (0)

// ---------------------------------------------------------------------------
template<bool LOCAL>
__device__ __forceinline__ void run_group(
    int group, int lrank, int tid, int lane, int w, int l15, int lk8,
    const float* __restrict__ x,
    const float* __restrict__ Wih1, const float* __restrict__ Whh1,
    const float* __restrict__ bih1, const float* __restrict__ bhh1,
    const float* __restrict__ Wih2, const float* __restrict__ Whh2,
    const float* __restrict__ bih2, const float* __restrict__ bhh2,
    const float* __restrict__ Wlin, const float* __restrict__ blin,
    float* __restrict__ out, unsigned char* __restrict__ gb,
    float (*red)[16][97], volatile unsigned* shm)
{
    unsigned* fL1 = (unsigned*)(gb + G_FL1);
    unsigned* fH2 = (unsigned*)(gb + G_FH2);
    unsigned* eL1 = (unsigned*)(gb + G_EL1);
    unsigned* eH2 = (unsigned*)(gb + G_EH2);
    float*    Pb  = (float*)(gb + G_PB);       // [4][16][2][24]
    const int kb0 = w * 192;

    if (lrank < 8) {
        // ========================= L1 role ==================================
        const int c = lrank;
        const int col0 = c * 96;

        s16x8 whi[6][6], wlo[6][6];
#pragma unroll
        for (int ks = 0; ks < 6; ks++)
#pragma unroll
            for (int nt = 0; nt < 6; nt++)
                load_wfrag(Whh1, col0 + nt * 16 + l15, kb0 + ks * 32 + lk8,
                           whi[ks][nt], wlo[ks][nt]);

        const int er = tid >> 4;                // row 0..15
        const int ec0 = (tid & 15) * 6;         // 6 consecutive cols
        const int b = group * GROWS + er;
        float bs[6], wi0[6], wi1[6];
#pragma unroll
        for (int j = 0; j < 6; j++) {
            int cg = col0 + ec0 + j;
            bs[j] = bih1[cg] + bhh1[cg];
            wi0[j] = Wih1[cg * 2 + 0];
            wi1[j] = Wih1[cg * 2 + 1];
        }
        const int ov = tid >> 5;                // 0..3 (tid<128)
        const int oj = tid & 31;
        const int orow = 2 * c + (ov >> 1);
        const int ooo = ov & 1;
        const float blv = blin[ooo];

        unsigned fh2c = 0, fl1c = 0;

        for (int t = 0; t < T_LEN; t++) {
            const int rs = (t + 3) & 3;         // h1(t-1) slot
            const int wsl = t & 3;              // h1(t) slot
            float x0 = x[b * 2048 + t];
            float x1 = x[b * 2048 + 1024 + t];

            // Top-of-iter off-path: fH2 gate (h1-slot guard) + out(t-3).
            // No inv: P read via atomics; slot guard is write-only.
            if (t >= 3) {
                if constexpr (LOCAL)
                    fh2c = wait_ep(eH2, fH2, 24, (unsigned)(t - 2), tid, lrank, fh2c, false, &shm[0]);
                else
                    wait_agent(fH2, 24, (unsigned)(t - 2), tid, false);
                if (tid < 128) {
                    float p = 0.f;
                    if (oj < 24)
                        p = __uint_as_float(rdp<LOCAL>((unsigned*)
                            (Pb + ((((t - 3) & 3) * 16 + orow) * 2 + ooo) * 24 + oj)));
#pragma unroll
                    for (int o = 16; o; o >>= 1) p += __shfl_down(p, o, 32);
                    if (oj == 0) out[(group * GROWS + orow) * 2048 + ooo * 1024 + (t - 3)] = p + blv;
                }
            }

            if (t) {
                if constexpr (LOCAL)
                    fl1c = wait_ep(eL1, fL1, 8, (unsigned)t, tid, lrank, fl1c, true, &shm[1]);
                else
                    wait_agent(fL1, 8, (unsigned)t, tid, true);
            }

            const unsigned short* Hh = (const unsigned short*)(gb + G_H1 + rs * 2 * HB_SZ);
            const unsigned short* Hl = (const unsigned short*)(gb + G_H1 + rs * 2 * HB_SZ + HB_SZ);
            s16x8 ah[6], al[6];
            ld6(Hh + l15 * H + kb0 + lk8, ah);
            ld6(Hl + l15 * H + kb0 + lk8, al);

            fx4 acc[6];
#pragma unroll
            for (int nt = 0; nt < 6; nt++) acc[nt] = fx4{0.f, 0.f, 0.f, 0.f};
#pragma unroll
            for (int ks = 0; ks < 6; ks++)
#pragma unroll
                for (int nt = 0; nt < 6; nt++) {
                    acc[nt] = mfma16(ah[ks], whi[ks][nt], acc[nt]);
                    acc[nt] = mfma16(ah[ks], wlo[ks][nt], acc[nt]);
                    acc[nt] = mfma16(al[ks], whi[ks][nt], acc[nt]);
                }

#pragma unroll
            for (int nt = 0; nt < 6; nt++)
#pragma unroll
                for (int i = 0; i < 4; i++)
                    red[w][(lane >> 4) * 4 + i][nt * 16 + l15] = acc[nt][i];
            __syncthreads();

            unsigned hw[3], lw[3];
#pragma unroll
            for (int jj = 0; jj < 3; jj++) {
                unsigned hp = 0, lp = 0;
#pragma unroll
                for (int k = 0; k < 2; k++) {
                    int j = jj * 2 + k;
                    int cc = ec0 + j;
                    float v = red[0][er][cc] + red[1][er][cc] + red[2][er][cc] + red[3][er][cc];
                    v += x0 * wi0[j] + x1 * wi1[j] + bs[j];
                    v = tanhf(v);
                    unsigned short hb = f2bf(v);
                    unsigned short lb = f2bf(v - bf2f(hb));
                    hp |= ((unsigned)hb) << (16 * k);
                    lp |= ((unsigned)lb) << (16 * k);
                }
                hw[jj] = hp; lw[jj] = lp;
            }

            unsigned* Dh = (unsigned*)(gb + G_H1 + wsl * 2 * HB_SZ) + ((long)er * H + col0 + ec0) / 2;
            unsigned* Dl = (unsigned*)(gb + G_H1 + wsl * 2 * HB_SZ + HB_SZ) + ((long)er * H + col0 + ec0) / 2;
            std32<LOCAL>(Dh + 0, hw[0]); std32<LOCAL>(Dh + 1, hw[1]); std32<LOCAL>(Dh + 2, hw[2]);
            std32<LOCAL>(Dl + 0, lw[0]); std32<LOCAL>(Dl + 1, lw[1]); std32<LOCAL>(Dl + 2, lw[2]);

            DRAIN();
            if constexpr (LOCAL)
                arrive_pub(fL1 + c, (unsigned)(t + 1), fL1, 8, c, eL1, tid);
            else if (tid == 0)
                st_ag(fL1 + c, (unsigned)(t + 1));
        }

        // tail: P(T-3..T-1)
        if constexpr (LOCAL)
            fh2c = wait_ep(eH2, fH2, 24, (unsigned)T_LEN, tid, lrank, fh2c, false, &shm[0]);
        else
            wait_agent(fH2, 24, (unsigned)T_LEN, tid, false);
        if (tid < 128) {
#pragma unroll
            for (int par = 0; par < 3; par++) {
                int tt = T_LEN - 3 + par;
                float p = 0.f;
                if (oj < 24)
                    p = __uint_as_float(rdp<LOCAL>((unsigned*)
                        (Pb + (((tt & 3) * 16 + orow) * 2 + ooo) * 24 + oj)));
#pragma unroll
                for (int o = 16; o; o >>= 1) p += __shfl_down(p, o, 32);
                if (oj == 0) out[(group * GROWS + orow) * 2048 + ooo * 1024 + tt] = p + blv;
            }
        }
    } else {
        // ========================= L2 role ==================================
        const int q = lrank - 8;         // 0..23
        const int col0 = q * 32;

        s16x8 ghi[2][6], glo[2][6], ihi[2][6], ilo[2][6];
#pragma unroll
        for (int nt = 0; nt < 2; nt++)
#pragma unroll
            for (int ks = 0; ks < 6; ks++) {
                load_wfrag(Whh2, col0 + nt * 16 + l15, kb0 + ks * 32 + lk8, ghi[nt][ks], glo[nt][ks]);
                load_wfrag(Wih2, col0 + nt * 16 + l15, kb0 + ks * 32 + lk8, ihi[nt][ks], ilo[nt][ks]);
            }

        const int er = tid >> 4;             // 0..15
        const int ec0 = (tid & 15) * 2;      // 0..30
        const float bsA = bih2[col0 + ec0] + bhh2[col0 + ec0];
        const float bsB = bih2[col0 + ec0 + 1] + bhh2[col0 + ec0 + 1];

        const int ro = tid >> 1, oo = tid & 1;   // tid<32
        float wl[32];
        if (tid < 32) {
#pragma unroll
            for (int cc = 0; cc < 32; cc++) wl[cc] = Wlin[oo * H + col0 + cc];
        }

        unsigned fh2c = 0, fl1c = 0;

        for (int t = 0; t < T_LEN; t++) {
            const int rb = (t + 1) & 1;     // h2(t-1) slot
            const int wb = t & 1;           // h2(t) slot
            const int hs = t & 3;           // h1(t) slot

            if (t) {
                if constexpr (LOCAL)
                    fh2c = wait_ep(eH2, fH2, 24, (unsigned)t, tid, lrank, fh2c, true, &shm[2]);
                else
                    wait_agent(fH2, 24, (unsigned)t, tid, true);
            }

            // phase 1: h2(t-1) @ W_hh2^T (overlaps h1(t) production)
            const unsigned short* Gh = (const unsigned short*)(gb + G_H2 + rb * 2 * HB_SZ);
            const unsigned short* Gl = (const unsigned short*)(gb + G_H2 + rb * 2 * HB_SZ + HB_SZ);
            s16x8 ah[6], al[6];
            ld6(Gh + l15 * H + kb0 + lk8, ah);
            ld6(Gl + l15 * H + kb0 + lk8, al);

            fx4 a2[2];
            a2[0] = fx4{0.f, 0.f, 0.f, 0.f};
            a2[1] = fx4{0.f, 0.f, 0.f, 0.f};
#pragma unroll
            for (int ks = 0; ks < 6; ks++)
#pragma unroll
                for (int nt = 0; nt < 2; nt++) {
                    a2[nt] = mfma16(ah[ks], ghi[nt][ks], a2[nt]);
                    a2[nt] = mfma16(ah[ks], glo[nt][ks], a2[nt]);
                    a2[nt] = mfma16(al[ks], ghi[nt][ks], a2[nt]);
                }

            if constexpr (LOCAL)
                fl1c = wait_ep(eL1, fL1, 8, (unsigned)(t + 1), tid, lrank, fl1c, true, &shm[3]);
            else
                wait_agent(fL1, 8, (unsigned)(t + 1), tid, true);

            // phase 3: += h1(t) @ W_ih2^T
            const unsigned short* Hh = (const unsigned short*)(gb + G_H1 + hs * 2 * HB_SZ);
            const unsigned short* Hl = (const unsigned short*)(gb + G_H1 + hs * 2 * HB_SZ + HB_SZ);
            ld6(Hh + l15 * H + kb0 + lk8, ah);
            ld6(Hl + l15 * H + kb0 + lk8, al);
#pragma unroll
            for (int ks = 0; ks < 6; ks++)
#pragma unroll
                for (int nt = 0; nt < 2; nt++) {
                    a2[nt] = mfma16(ah[ks], ihi[nt][ks], a2[nt]);
                    a2[nt] = mfma16(ah[ks], ilo[nt][ks], a2[nt]);
                    a2[nt] = mfma16(al[ks], ihi[nt][ks], a2[nt]);
                }

#pragma unroll
            for (int nt = 0; nt < 2; nt++)
#pragma unroll
                for (int i = 0; i < 4; i++)
                    red[w][(lane >> 4) * 4 + i][nt * 16 + l15] = a2[nt][i];
            __syncthreads();

            float v0 = red[0][er][ec0] + red[1][er][ec0] + red[2][er][ec0] + red[3][er][ec0] + bsA;
            float v1 = red[0][er][ec0 + 1] + red[1][er][ec0 + 1] + red[2][er][ec0 + 1] + red[3][er][ec0 + 1] + bsB;
            v0 = tanhf(v0); v1 = tanhf(v1);
            unsigned short hb0 = f2bf(v0), hb1 = f2bf(v1);
            unsigned hp = ((unsigned)hb0) | (((unsigned)hb1) << 16);
            unsigned lp = ((unsigned)f2bf(v0 - bf2f(hb0))) | (((unsigned)f2bf(v1 - bf2f(hb1))) << 16);
            unsigned* Dh = (unsigned*)(gb + G_H2 + wb * 2 * HB_SZ) + ((long)er * H + col0 + ec0) / 2;
            unsigned* Dl = (unsigned*)(gb + G_H2 + wb * 2 * HB_SZ + HB_SZ) + ((long)er * H + col0 + ec0) / 2;
            std32<LOCAL>(Dh, hp);
            std32<LOCAL>(Dl, lp);
            red[0][er][ec0] = v0;
            red[0][er][ec0 + 1] = v1;
            __syncthreads();

            if (tid < 32) {
                float s = 0.f;
#pragma unroll
                for (int cc = 0; cc < 32; cc++) s += red[0][ro][cc] * wl[cc];
                std32<LOCAL>((unsigned*)&Pb[(((t & 3) * 16 + ro) * 2 + oo) * 24 + q],
                             __float_as_uint(s));
            }

            DRAIN();
            if constexpr (LOCAL)
                arrive_pub(fH2 + q, (unsigned)(t + 1), fH2, 24, q, eH2, tid);
            else if (tid == 0)
                st_ag(fH2 + q, (unsigned)(t + 1));
        }
    }
}

// ---------------------------------------------------------------------------
__global__ __launch_bounds__(256, 1) void rnn_persist(
    const float* __restrict__ x,
    const float* __restrict__ Wih1, const float* __restrict__ Whh1,
    const float* __restrict__ bih1, const float* __restrict__ bhh1,
    const float* __restrict__ Wih2, const float* __restrict__ Whh2,
    const float* __restrict__ bih2, const float* __restrict__ bhh2,
    const float* __restrict__ Wlin, const float* __restrict__ blin,
    float* __restrict__ out, unsigned char* __restrict__ ws)
{
    const int wg = blockIdx.x;
    const int tid = threadIdx.x;
    const int lane = tid & 63;
    const int w = tid >> 6;
    const int l15 = lane & 15;
    const int lk8 = (lane >> 4) * 8;

    __shared__ float red[4][16][97];
    __shared__ int iscr[256];
    __shared__ unsigned shm[4];

    // ---- runtime XCD discovery (agent scope, r5/r6/r12-proven) -------------
    unsigned* map = (unsigned*)(ws + MAP_OFF);
    unsigned* kbr = (unsigned*)(ws + KBR_OFF);

    int key;
    asm volatile("s_getreg_b32 %0, hwreg(HW_REG_XCC_ID, 0, 4)" : "=s"(key));
    key &= 0xF;

    if (tid == 0) st_ag(map + wg, (unsigned)(key + 1));
    unsigned kj;
    {
        long spin = 0;
        for (;;) {
            kj = ld_ag(map + tid);
            if (kj) break;
            __builtin_amdgcn_s_sleep(2);
            if (++spin > (1L << 20)) break;
        }
    }
    int contrib = (((int)kj - 1) < key || (((int)kj - 1) == key && tid < wg)) ? 1 : 0;
    iscr[tid] = contrib;
    __syncthreads();
#pragma unroll
    for (int s = 128; s; s >>= 1) {
        if (tid < s) iscr[tid] += iscr[tid + s];
        __syncthreads();
    }
    const int rank = iscr[0];
    __syncthreads();
    const int group = rank >> 5, lrank = rank & 31;

    if (tid == 0) st_ag(kbr + rank, (unsigned)(key + 1));
    unsigned kv;
    {
        long spin = 0;
        for (;;) {
            kv = ld_ag(kbr + tid);
            if (kv) break;
            __builtin_amdgcn_s_sleep(2);
            if (++spin > (1L << 20)) break;
        }
    }
    int eq = ((int)kv - 1 == key) ? 1 : 0;
    int bad = ((tid >> 5) == group && !eq) ? 1 : 0;
    iscr[tid] = eq | (bad << 16);
    __syncthreads();
#pragma unroll
    for (int s = 128; s; s >>= 1) {
        if (tid < s) iscr[tid] += iscr[tid + s];
        __syncthreads();
    }
    const int r0 = iscr[0];
    __syncthreads();
    const bool local = ((r0 & 0xFFFF) == 32) && ((r0 >> 16) == 0);

    unsigned char* gb = ws + GRP_BASE + (size_t)group * GRP_STRIDE;

    if (local)
        run_group<true>(group, lrank, tid, lane, w, l15, lk8,
                        x, Wih1, Whh1, bih1, bhh1, Wih2, Whh2, bih2, bhh2,
                        Wlin, blin, out, gb, red, shm);
    else
        run_group<false>(group, lrank, tid, lane, w, l15, lk8,
                         x, Wih1, Whh1, bih1, bhh1, Wih2, Whh2, bih2, bhh2,
                         Wlin, blin, out, gb, red, shm);
}

extern "C" void kernel_launch(void* const* d_in, const int* in_sizes, int n_in,
                              void* d_out, int out_size, void* d_ws, size_t ws_size,
                              hipStream_t stream) {
    const float* x    = (const float*)d_in[0];
    const float* Wih1 = (const float*)d_in[1];
    const float* Whh1 = (const float*)d_in[2];
    const float* bih1 = (const float*)d_in[3];
    const float* bhh1 = (const float*)d_in[4];
    const float* Wih2 = (const float*)d_in[5];
    const float* Whh2 = (const float*)d_in[6];
    const float* bih2 = (const float*)d_in[7];
    const float* bhh2 = (const float*)d_in[8];
    const float* Wlin = (const float*)d_in[9];
    const float* blin = (const float*)d_in[10];

    // Zero discovery tables, flags, epochs, h-state (initial h = 0).
    hipMemsetAsync(d_ws, 0, WS_TOTAL, stream);

    rnn_persist<<<NWG, 256, 0, stream>>>(x, Wih1, Whh1, bih1, bhh1,
                                         Wih2, Whh2, bih2, bhh2,
                                         Wlin, blin, (float*)d_out,
                                         (unsigned char*)d_ws);
}